// Round 1
// baseline (669.928 us; speedup 1.0000x reference)
//
#include <hip/hip_runtime.h>
#include <stdint.h>

// Problem constants (match reference)
#define KH 8
#define HD 128
#define GD 64
#define UD 128
#define WPAD 136   // 128 + 8 bf16 pad: row stride 68 words -> bank-balanced ds_read_b128
#define NPB 64     // nodes per block (4 waves x 16)

typedef __attribute__((ext_vector_type(8))) short short8;   // 8 x bf16 (guide: frag_ab)
typedef __attribute__((ext_vector_type(4))) float f32x4;    // MFMA C/D frag

__device__ __forceinline__ unsigned short f2bf(float x) {
    union { float f; unsigned u; } v; v.f = x;
    return (unsigned short)((v.u + 0x7fffu + ((v.u >> 16) & 1u)) >> 16);  // RNE
}

// ---------------- pre-kernel: bf16-convert + transpose weights into padded LDS images ----
// ws layout (bf16 elements):
//   [0)                : WghT [k][g][WPAD]  = Wgh[k][h][g]     (8*64*136)
//   [KH*GD*WPAD)       : WuhT [k][u][WPAD]  = Wuh[k][h][u]     (8*128*136)
//   [... + KH*UD*WPAD) : WgvT [g][WPAD]     = Wgv[h][g]        (64*136)
__global__ void prep_weights(const float* __restrict__ Wgv,
                             const float* __restrict__ Wgh,
                             const float* __restrict__ Wuh,
                             unsigned short* __restrict__ ws) {
    const int wghN = KH * GD * WPAD;
    const int wuhN = KH * UD * WPAD;
    const int wgvN = GD * WPAD;
    int idx = blockIdx.x * 256 + threadIdx.x;
    if (idx >= wghN + wuhN + wgvN) return;
    float val = 0.f;
    if (idx < wghN) {
        int k = idx / (GD * WPAD), rem = idx % (GD * WPAD);
        int g = rem / WPAD, h = rem % WPAD;
        if (h < HD) val = Wgh[((size_t)k * HD + h) * GD + g];
    } else if (idx < wghN + wuhN) {
        int j = idx - wghN;
        int k = j / (UD * WPAD), rem = j % (UD * WPAD);
        int u = rem / WPAD, h = rem % WPAD;
        if (h < HD) val = Wuh[((size_t)k * HD + h) * UD + u];
    } else {
        int j = idx - wghN - wuhN;
        int g = j / WPAD, h = j % WPAD;
        if (h < HD) val = Wgv[(size_t)h * GD + g];
    }
    ws[idx] = f2bf(val);
}

// async flat copy of 1KB chunks global->LDS (dest layout == source layout, pad baked in)
__device__ __forceinline__ void cp_lds(const unsigned short* gs, unsigned short* ld,
                                       int nch, int wave, int lane) {
    for (int i = wave; i < nch; i += 4) {
        __builtin_amdgcn_global_load_lds(
            (const __attribute__((address_space(1))) unsigned int*)(gs + i * 512 + lane * 8),
            (__attribute__((address_space(3))) unsigned int*)(ld + i * 512),
            16, 0, 0);
    }
}

// ---------------- main kernel ----------------------------------------------------------
// Per block: 64 nodes. Per wave: 16-node MFMA strip over full feature width.
// U = (sum_k g_k * (H_k @ Wuh_k)) / (sum_k g_k), g_k = exp(lrelu(<H_k@Wgh_k, vt@Wgv>)/8)
__launch_bounds__(256, 3)
__global__ void ghatt_main(const float* __restrict__ vt, const float* __restrict__ H,
                           const unsigned short* __restrict__ ws,
                           float* __restrict__ out, int N) {
    __shared__ unsigned short lds_h [NPB * WPAD];  // 17408 B  (vt tile in phase0, H tile in k-loop)
    __shared__ unsigned short lds_wg[GD * WPAD];   // 17408 B  (WgvT phase0, WghT[k] in k-loop)
    __shared__ unsigned short lds_wu[GD * WPAD];   // 17408 B  (WuhT[k] half: 64 u-rows)
    // total 52224 B -> 3 blocks/CU

    const int tid  = threadIdx.x;
    const int wave = tid >> 6;
    const int lane = tid & 63;
    const int cc   = lane & 15;   // MFMA col / A-row index
    const int q    = lane >> 4;   // quad
    const int nodebase = blockIdx.x * NPB;

    const unsigned short* wghT = ws;
    const unsigned short* wuhT = ws + (size_t)KH * GD * WPAD;
    const unsigned short* wgvT = ws + (size_t)KH * GD * WPAD + (size_t)KH * UD * WPAD;

    float4 hreg[8];   // prefetch regs: 8 x float4 per thread = one 64x128 f32 tile per block

    // ---- phase 0: stage vt tile (bf16) + WgvT; compute g_key fragments (stay in regs) --
#pragma unroll
    for (int i = 0; i < 8; i++) {
        int f = tid + 256 * i, row = f >> 5, c4 = f & 31;
        int node = nodebase + row;
        float4 z; z.x = z.y = z.z = z.w = 0.f;
        float4 v = (node < N) ? ((const float4*)vt)[(size_t)node * 32 + c4] : z;
        short4 b;
        b.x = (short)f2bf(v.x); b.y = (short)f2bf(v.y);
        b.z = (short)f2bf(v.z); b.w = (short)f2bf(v.w);
        *(short4*)&lds_h[row * WPAD + c4 * 4] = b;
    }
    cp_lds(wgvT, lds_wg, 17, wave, lane);
    __syncthreads();

    // prefetch H k=0 while doing the g_key MFMAs
#pragma unroll
    for (int i = 0; i < 8; i++) {
        int f = tid + 256 * i, row = f >> 5, c4 = f & 31;
        int node = nodebase + row;
        float4 z; z.x = z.y = z.z = z.w = 0.f;
        hreg[i] = (node < N) ? ((const float4*)H)[(size_t)node * 32 + c4] : z;
    }

    f32x4 gkeyv[4];   // g_key in C-layout: row(node)=4q+r, col(g)=cc+16t  — same layout as gq!
    {
        short8 va[4];
#pragma unroll
        for (int kb = 0; kb < 4; kb++)
            va[kb] = *(const short8*)&lds_h[(wave * 16 + cc) * WPAD + kb * 32 + q * 8];
#pragma unroll
        for (int t = 0; t < 4; t++) {
            f32x4 acc = {0.f, 0.f, 0.f, 0.f};
#pragma unroll
            for (int kb = 0; kb < 4; kb++) {
                short8 vb = *(const short8*)&lds_wg[(t * 16 + cc) * WPAD + kb * 32 + q * 8];
                acc = __builtin_amdgcn_mfma_f32_16x16x32_bf16(va[kb], vb, acc, 0, 0, 0);
            }
            gkeyv[t] = acc;
        }
    }

    f32x4 Uacc[8];
#pragma unroll
    for (int t = 0; t < 8; t++) { Uacc[t].x = Uacc[t].y = Uacc[t].z = Uacc[t].w = 0.f; }
    float den[4] = {0.f, 0.f, 0.f, 0.f};

    // ---- k loop: single pass over H -----------------------------------------------------
    for (int k = 0; k < KH; k++) {
        __syncthreads();   // prev compute done reading LDS; drains hreg prefetch
#pragma unroll
        for (int i = 0; i < 8; i++) {
            int f = tid + 256 * i, row = f >> 5, c4 = f & 31;
            short4 b;
            b.x = (short)f2bf(hreg[i].x); b.y = (short)f2bf(hreg[i].y);
            b.z = (short)f2bf(hreg[i].z); b.w = (short)f2bf(hreg[i].w);
            *(short4*)&lds_h[row * WPAD + c4 * 4] = b;
        }
        cp_lds(wghT + (size_t)k * (GD * WPAD), lds_wg, 17, wave, lane);
        cp_lds(wuhT + (size_t)k * (UD * WPAD), lds_wu, 17, wave, lane);  // u 0..63
        __syncthreads();

        if (k < KH - 1) {  // prefetch next H tile, overlaps compute below
#pragma unroll
            for (int i = 0; i < 8; i++) {
                int f = tid + 256 * i, row = f >> 5, c4 = f & 31;
                int node = nodebase + row;
                float4 z; z.x = z.y = z.z = z.w = 0.f;
                hreg[i] = (node < N) ? ((const float4*)H)[((size_t)(k + 1) * N + node) * 32 + c4] : z;
            }
        }

        short8 va[4];   // A frags: H[node=wave*16+cc][h], reused for gq and both HT halves
#pragma unroll
        for (int kb = 0; kb < 4; kb++)
            va[kb] = *(const short8*)&lds_h[(wave * 16 + cc) * WPAD + kb * 32 + q * 8];

        // g_query = H @ Wgh[k]  (C-layout, matches gkeyv)
        f32x4 gqv[4];
#pragma unroll
        for (int t = 0; t < 4; t++) {
            f32x4 acc = {0.f, 0.f, 0.f, 0.f};
#pragma unroll
            for (int kb = 0; kb < 4; kb++) {
                short8 vb = *(const short8*)&lds_wg[(t * 16 + cc) * WPAD + kb * 32 + q * 8];
                acc = __builtin_amdgcn_mfma_f32_16x16x32_bf16(va[kb], vb, acc, 0, 0, 0);
            }
            gqv[t] = acc;
        }

        // score: per-row dot over g, reduced across the 16 column-lanes of each quad
        float part[4];
#pragma unroll
        for (int r = 0; r < 4; r++)
            part[r] = gqv[0][r] * gkeyv[0][r] + gqv[1][r] * gkeyv[1][r]
                    + gqv[2][r] * gkeyv[2][r] + gqv[3][r] * gkeyv[3][r];
#pragma unroll
        for (int m2 = 1; m2 < 16; m2 <<= 1) {
#pragma unroll
            for (int r = 0; r < 4; r++) part[r] += __shfl_xor(part[r], m2);
        }
        float gg[4];
#pragma unroll
        for (int r = 0; r < 4; r++) {
            float x = part[r];
            x = (x >= 0.f) ? x : 0.01f * x;      // LeakyReLU(0.01)
            gg[r] = __expf(x * 0.125f);          // / sqrt(64)
            den[r] += gg[r];
        }

        // H_trans half 0 (u 0..63): U += g * (H @ Wuh)
#pragma unroll
        for (int t = 0; t < 4; t++) {
            f32x4 acc = {0.f, 0.f, 0.f, 0.f};
#pragma unroll
            for (int kb = 0; kb < 4; kb++) {
                short8 vb = *(const short8*)&lds_wu[(t * 16 + cc) * WPAD + kb * 32 + q * 8];
                acc = __builtin_amdgcn_mfma_f32_16x16x32_bf16(va[kb], vb, acc, 0, 0, 0);
            }
#pragma unroll
            for (int r = 0; r < 4; r++) Uacc[t][r] += gg[r] * acc[r];
        }

        __syncthreads();
        cp_lds(wuhT + (size_t)k * (UD * WPAD) + (size_t)64 * WPAD, lds_wu, 17, wave, lane); // u 64..127
        __syncthreads();

#pragma unroll
        for (int t = 0; t < 4; t++) {
            f32x4 acc = {0.f, 0.f, 0.f, 0.f};
#pragma unroll
            for (int kb = 0; kb < 4; kb++) {
                short8 vb = *(const short8*)&lds_wu[(t * 16 + cc) * WPAD + kb * 32 + q * 8];
                acc = __builtin_amdgcn_mfma_f32_16x16x32_bf16(va[kb], vb, acc, 0, 0, 0);
            }
#pragma unroll
            for (int r = 0; r < 4; r++) Uacc[4 + t][r] += gg[r] * acc[r];
        }
    }

    // ---- epilogue: normalize, lrelu, store ---------------------------------------------
    float inv[4];
#pragma unroll
    for (int r = 0; r < 4; r++) inv[r] = 1.f / den[r];
#pragma unroll
    for (int t = 0; t < 8; t++) {
#pragma unroll
        for (int r = 0; r < 4; r++) {
            float u = Uacc[t][r] * inv[r];
            u = (u >= 0.f) ? u : 0.01f * u;
            int node = nodebase + wave * 16 + 4 * q + r;
            if (node < N) out[(size_t)node * UD + t * 16 + cc] = u;
        }
    }
}

extern "C" void kernel_launch(void* const* d_in, const int* in_sizes, int n_in,
                              void* d_out, int out_size, void* d_ws, size_t ws_size,
                              hipStream_t stream) {
    const float* vt  = (const float*)d_in[0];
    const float* H   = (const float*)d_in[1];
    const float* Wgv = (const float*)d_in[2];
    const float* Wgh = (const float*)d_in[3];
    const float* Wuh = (const float*)d_in[4];
    float* out = (float*)d_out;
    unsigned short* wsw = (unsigned short*)d_ws;

    const int N = in_sizes[0] / HD;   // vt is [N,128]

    // weight prep: 217600 bf16 elements = 425 KB of d_ws (assumed ws_size >= 435200 B)
    const int prepTot = KH * GD * WPAD + KH * UD * WPAD + GD * WPAD;
    hipLaunchKernelGGL(prep_weights, dim3((prepTot + 255) / 256), dim3(256), 0, stream,
                       Wgv, Wgh, Wuh, wsw);

    hipLaunchKernelGGL(ghatt_main, dim3((N + NPB - 1) / NPB), dim3(256), 0, stream,
                       vt, H, wsw, out, N);
}